// Round 14
// baseline (179.734 us; speedup 1.0000x reference)
//
#include <hip/hip_runtime.h>
#include <hip/hip_bf16.h>

// Problem constants
#define B_   8
#define S_   1024
#define D_   768
#define H_   12
#define HD_  64
#define BS_  (B_*S_)     // 8192 rows
#define N3_  (3*D_)      // 2304

typedef __attribute__((ext_vector_type(8))) short short8;   // 8 x bf16 (4 VGPRs)
typedef __attribute__((ext_vector_type(4))) float f32x4;

__device__ __forceinline__ short8 ld8(const __hip_bfloat16* p) {
    return *reinterpret_cast<const short8*>(p);
}
__device__ __forceinline__ void st8(__hip_bfloat16* p, short8 v) {
    *reinterpret_cast<short8*>(p) = v;
}
__device__ __forceinline__ f32x4 mfma16(short8 a, short8 b, f32x4 c) {
    return __builtin_amdgcn_mfma_f32_16x16x32_bf16(a, b, c, 0, 0, 0);
}
// async global->LDS, 16B/lane; LDS dest = wave-uniform base + lane*16 (HW adds)
__device__ __forceinline__ void async16(const __hip_bfloat16* g, __hip_bfloat16* l) {
    __builtin_amdgcn_global_load_lds((const __attribute__((address_space(1))) void*)g,
                                     (__attribute__((address_space(3))) void*)l,
                                     16, 0, 0);
}
__device__ __forceinline__ float fast_exp2(float x) {
#if __has_builtin(__builtin_amdgcn_exp2f)
    return __builtin_amdgcn_exp2f(x);
#else
    return __expf(x * 0.69314718056f);
#endif
}

// ---------------- fused prep: cast X + transpose both weights --------------
#define PREP_CAST_BLK 6144          // BS_*D_ / (256*4)
#define PREP_WQKV_BLK 1728          // (N3_/32)*(D_/32)
#define PREP_WOUT_BLK 576           // (D_/32)*(D_/32)
__global__ __launch_bounds__(256)
void prep(const float* __restrict__ X, __hip_bfloat16* __restrict__ Xbf,
          const float* __restrict__ Wqkv, __hip_bfloat16* __restrict__ WqkvT,
          const float* __restrict__ Wout, __hip_bfloat16* __restrict__ WoutT) {
    __shared__ float tile[32][33];
    int b = blockIdx.x, tid = threadIdx.x;
    if (b < PREP_CAST_BLK) {
        int i = (b * 256 + tid) * 4;
        float4 v = *reinterpret_cast<const float4*>(X + i);
        __hip_bfloat16 tmp[4];
        tmp[0] = __float2bfloat16(v.x);
        tmp[1] = __float2bfloat16(v.y);
        tmp[2] = __float2bfloat16(v.z);
        tmp[3] = __float2bfloat16(v.w);
        *reinterpret_cast<ushort4*>(Xbf + i) =
            *reinterpret_cast<const ushort4*>(tmp);   // one 8B store, not 4x2B
        return;
    }
    const float* in; __hip_bfloat16* out; int Rr, Cc, bx, by;
    if (b < PREP_CAST_BLK + PREP_WQKV_BLK) {
        int sub = b - PREP_CAST_BLK;
        bx = sub % (N3_ / 32); by = sub / (N3_ / 32);
        in = Wqkv; out = WqkvT; Rr = D_; Cc = N3_;
    } else {
        int sub = b - PREP_CAST_BLK - PREP_WQKV_BLK;
        bx = sub % (D_ / 32); by = sub / (D_ / 32);
        in = Wout; out = WoutT; Rr = D_; Cc = D_;
    }
    int tx = tid & 31, ty = tid >> 5;
    int c0 = bx * 32, r0 = by * 32;
    for (int i = ty; i < 32; i += 8)
        tile[i][tx] = in[(size_t)(r0 + i) * Cc + c0 + tx];
    __syncthreads();
    for (int i = ty; i < 32; i += 8)
        out[(size_t)(c0 + i) * Rr + r0 + tx] = __float2bfloat16(tile[tx][i]);
}

// ---------------- QKV GEMM: round-3 champion, FROZEN -----------------------
// Ledger closed: traffic (R3 null), occupancy up/down (R5/R1/R2 regress),
// stagger (R10 null), barrier-free 1-wave (R11: 2.3x WORSE -- per-SIMD wave
// parallelism is load-bearing). 48.2us is this tile/shape's structural
// optimum. Grid-quantization fixes (smaller tiles / split-K) analyzed R14:
// all net-negative (step time is sync-dominated). Do not touch.
__global__ __launch_bounds__(256)
void gemm_qkv(const __hip_bfloat16* __restrict__ A,
              const __hip_bfloat16* __restrict__ Bt,
              const float* __restrict__ bqkv,
              __hip_bfloat16* __restrict__ Qb,
              __hip_bfloat16* __restrict__ Kb,
              __hip_bfloat16* __restrict__ Vtb) {
    __shared__ __align__(16) char smem[49152];           // 3 x (As 8K + Bs 8K)
    __hip_bfloat16* Ct = (__hip_bfloat16*)smem;          // [128][132] epilogue

    int tid = threadIdx.x, wave = tid >> 6, lane = tid & 63;
    int ln = lane & 15, quad = lane >> 4;
    int lin = blockIdx.y * 18 + blockIdx.x;              // 0..1151
    int work = (lin & 7) * 144 + (lin >> 3);
    int mbb = work / 18, nbb = work % 18;
    int mb = mbb * 128, nb = nbb * 128;
    int wm = (wave >> 1) * 64, wn = (wave & 1) * 64;

    f32x4 acc[4][4];
#pragma unroll
    for (int i = 0; i < 4; ++i)
#pragma unroll
        for (int j = 0; j < 4; ++j) acc[i][j] = (f32x4){0.f, 0.f, 0.f, 0.f};

    auto stage = [&](int k, int bufoff) {   // 4 async16 per thread
        __hip_bfloat16* Asb = (__hip_bfloat16*)(smem + bufoff);
        __hip_bfloat16* Bsb = Asb + 128 * 32;
#pragma unroll
        for (int it = 0; it < 2; ++it) {
            int c = it * 256 + tid;
            int row = c >> 2, cc = c & 3;
            int csw = cc ^ ((row >> 1) & 3);
            async16(A + (size_t)(mb + row) * D_ + k + csw * 8,
                    Asb + it * 2048 + wave * 512);
            async16(Bt + (size_t)(nb + row) * D_ + k + csw * 8,
                    Bsb + it * 2048 + wave * 512);
        }
    };

    auto compute = [&](int bufoff) {
        __hip_bfloat16* As = (__hip_bfloat16*)(smem + bufoff);
        __hip_bfloat16* Bs = As + 128 * 32;
        short8 a[4], b[4];
#pragma unroll
        for (int i = 0; i < 4; ++i) {
            int row = wm + i * 16 + ln;
            a[i] = ld8(As + row * 32 + ((quad ^ ((row >> 1) & 3)) << 3));
        }
#pragma unroll
        for (int j = 0; j < 4; ++j) {
            int row = wn + j * 16 + ln;
            b[j] = ld8(Bs + row * 32 + ((quad ^ ((row >> 1) & 3)) << 3));
        }
#pragma unroll
        for (int i = 0; i < 4; ++i)
#pragma unroll
            for (int j = 0; j < 4; ++j)
                acc[i][j] = mfma16(a[i], b[j], acc[i][j]);
    };

    stage(0, 0);
    stage(32, 16384);
    int cb = 0;
    for (int k = 0; k < D_ - 32; k += 32) {
        asm volatile("s_waitcnt vmcnt(4)" ::: "memory");  // oldest stage done
        asm volatile("s_barrier" ::: "memory");           // visible to all
        if (k + 64 < D_) {
            int sb = cb + 32768; if (sb >= 49152) sb -= 49152;
            stage(k + 64, sb);                            // distance-2 prefetch
        }
        compute(cb);
        cb += 16384; if (cb >= 49152) cb = 0;
    }
    asm volatile("s_waitcnt vmcnt(0)" ::: "memory");      // peeled last iter
    asm volatile("s_barrier" ::: "memory");
    compute(cb);
    __syncthreads();   // all compute done; LDS reusable for epilogue

    // ---- epilogue: one pass through LDS, coalesced 16B stores ----
    int which = nbb / 6;                // 0=Q, 1=K, 2=V
    int nbr = nb - which * D_;
    float qscale = (which == 0) ? (0.125f * 1.44269504089f) : 1.f;

#pragma unroll
    for (int j = 0; j < 4; ++j) {
        int col = wn + j * 16 + ln;
        float bias = bqkv[nb + col];
#pragma unroll
        for (int i = 0; i < 4; ++i)
#pragma unroll
            for (int r = 0; r < 4; ++r) {
                int row = wm + i * 16 + quad * 4 + r;
                __hip_bfloat16 v = __float2bfloat16((acc[i][j][r] + bias) * qscale);
                if (which != 2) Ct[row * 132 + col] = v;
                else            Ct[col * 132 + row] = v;    // [d][s]
            }
    }
    __syncthreads();

    int bb = mb >> 10, sb = mb & 1023;
    if (which != 2) {
        __hip_bfloat16* dst = (which == 0) ? Qb : Kb;
#pragma unroll
        for (int it = 0; it < 8; ++it) {
            int cc = it * 256 + tid;
            int row = cc >> 4, c8 = cc & 15;
            short8 v = ld8(Ct + row * 132 + c8 * 8);
            int gcol = nbr + c8 * 8;
            int h = gcol >> 6, d = gcol & 63;
            int s = sb + row;
            st8(dst + (((size_t)(bb * H_ + h)) * S_ + s) * HD_ + d, v);
        }
    } else {
#pragma unroll
        for (int it = 0; it < 8; ++it) {
            int cc = it * 256 + tid;
            int drow = cc >> 4, s8 = cc & 15;
            short8 v = ld8(Ct + drow * 132 + s8 * 8);
            int gd = nbr + drow;
            int h = gd >> 6, d = gd & 63;
            st8(Vtb + ((size_t)(bb * H_ + h) * HD_ + d) * S_ + sb + s8 * 8, v);
        }
    }
}

// ---------------- causal flash attention v5 (R9 best-measured, restored) ---
// R13's counted-vmcnt + dual-barrier variant was neutral-to-negative (179.3
// vs 178.0) -> per-iteration K/V drain is already covered; remaining cost is
// the in-iteration serial chain (QK^T->exp->Pbuf->PV). This is the R9
// champion: balanced strip pairing (2j,2j+1) + XCD-grouped heads + setprio
// + split-lgkm + single __syncthreads per kt.
__global__ __launch_bounds__(256, 3)
void attn_flash3(const __hip_bfloat16* __restrict__ Q,
                 const __hip_bfloat16* __restrict__ K,
                 const __hip_bfloat16* __restrict__ Vt,
                 __hip_bfloat16* __restrict__ attnbf) {
    __shared__ __hip_bfloat16 Kbuf[2][64 * 64];
    __shared__ __hip_bfloat16 Vbuf[2][64 * 64];
    __shared__ __hip_bfloat16 Pbuf[4][32 * 72];

    int tid = threadIdx.x;
    int wave = tid >> 6, lane = tid & 63;
    int ln = lane & 15, quad = lane >> 4;

    int lin = blockIdx.y * 8 + blockIdx.x;   // 0..767, dispatch order
    int xcd = lin & 7;
    int idx = lin >> 3;                      // 0..95
    int jj  = idx & 7;
    int bh  = (idx >> 3) * 8 + xcd;          // head group pinned to one XCD
    int r   = idx >> 5;                      // CU-round 0..2

    const int TBL1[8] = {4, 5, 6, 7, 0, 1, 2, 3};
    const int TBL2[8] = {6, 4, 2, 0, 7, 5, 3, 1};
    int jp = (r == 0) ? jj : (r == 1) ? TBL1[jj] : TBL2[jj];
    int strip = jp * 2 + (wave >> 1);        // waves 0,1 -> 2j; waves 2,3 -> 2j+1
    int qrow0 = strip * 64 + (wave & 1) * 32;
    int last_kt = jp * 2 + 1;

    const __hip_bfloat16* Qbh = Q + (size_t)bh * S_ * HD_;
    const __hip_bfloat16* Kbh = K + (size_t)bh * S_ * HD_;
    const __hip_bfloat16* Vbh = Vt + (size_t)bh * HD_ * S_;

    short8 aq[2][2];
#pragma unroll
    for (int rt = 0; rt < 2; ++rt)
#pragma unroll
        for (int ks = 0; ks < 2; ++ks)
            aq[rt][ks] = ld8(Qbh + (size_t)(qrow0 + rt * 16 + ln) * HD_ +
                             ks * 32 + quad * 8);

    f32x4 o[2][4];
    float l_run[2][4];
#pragma unroll
    for (int rt = 0; rt < 2; ++rt)
#pragma unroll
        for (int n = 0; n < 4; ++n) {
            o[rt][n] = (f32x4){0.f, 0.f, 0.f, 0.f};
            l_run[rt][n] = 0.f;
        }

    auto stage = [&](int kt, int buf) {
        const __hip_bfloat16* gK = Kbh + (size_t)kt * 64 * HD_;
#pragma unroll
        for (int it = 0; it < 2; ++it) {
            int p = it * 256 + tid;
            int row = p >> 3;
            int csw = (p & 7) ^ (row & 7);
            async16(gK + row * HD_ + csw * 8,
                    &Kbuf[buf][it * 2048 + wave * 512]);
            async16(Vbh + (size_t)row * S_ + kt * 64 + csw * 8,
                    &Vbuf[buf][it * 2048 + wave * 512]);
        }
    };

    stage(0, 0);
    __syncthreads();
    int cur = 0;

    for (int kt = 0; kt <= last_kt; ++kt) {
        int kbase = kt * 64;
        if (kt < last_kt) stage(kt + 1, cur ^ 1);

        if (kbase <= qrow0 + 31) {
            const __hip_bfloat16* Kc = Kbuf[cur];
            const __hip_bfloat16* Vc = Vbuf[cur];

            f32x4 s[2][4];
#pragma unroll
            for (int rt = 0; rt < 2; ++rt)
#pragma unroll
                for (int j = 0; j < 4; ++j) s[rt][j] = (f32x4){0.f, 0.f, 0.f, 0.f};
            __builtin_amdgcn_s_setprio(1);            // T5: favor MFMA wave
#pragma unroll
            for (int j = 0; j < 4; ++j) {
                int row = j * 16 + ln;
#pragma unroll
                for (int ks = 0; ks < 2; ++ks) {
                    short8 bk = ld8(&Kc[row * 64 +
                                        (((ks * 4 + quad) ^ (row & 7)) << 3)]);
#pragma unroll
                    for (int rt = 0; rt < 2; ++rt)
                        s[rt][j] = mfma16(aq[rt][ks], bk, s[rt][j]);
                }
            }
            __builtin_amdgcn_s_setprio(0);

            if (kbase + 63 > qrow0) {
#pragma unroll
                for (int rt = 0; rt < 2; ++rt)
#pragma unroll
                    for (int j = 0; j < 4; ++j) {
                        int key = kbase + j * 16 + ln;
#pragma unroll
                        for (int r2 = 0; r2 < 4; ++r2) {
                            int q = qrow0 + rt * 16 + quad * 4 + r2;
                            if (key > q) s[rt][j][r2] = -INFINITY;
                        }
                    }
            }

#pragma unroll
            for (int rt = 0; rt < 2; ++rt)
#pragma unroll
                for (int j = 0; j < 4; ++j)
#pragma unroll
                    for (int r2 = 0; r2 < 4; ++r2)
                        s[rt][j][r2] = fast_exp2(s[rt][j][r2]);
#pragma unroll
            for (int rt = 0; rt < 2; ++rt)
#pragma unroll
                for (int r2 = 0; r2 < 4; ++r2)
                    l_run[rt][r2] += (s[rt][0][r2] + s[rt][1][r2]) +
                                     (s[rt][2][r2] + s[rt][3][r2]);

            // P write-back: rt=0's 16 stores first, then rt=1's 16 (in-order
            // DS retire => lgkmcnt(15) releases rt=0 rows early).
#pragma unroll
            for (int rt = 0; rt < 2; ++rt)
#pragma unroll
                for (int j = 0; j < 4; ++j)
#pragma unroll
                    for (int r2 = 0; r2 < 4; ++r2)
                        Pbuf[wave][(rt * 16 + quad * 4 + r2) * 72 + j * 16 + ln] =
                            __float2bfloat16(s[rt][j][r2]);

            short8 ap[2][2];
            asm volatile("s_waitcnt lgkmcnt(15)" ::: "memory");
            __builtin_amdgcn_sched_barrier(0);
#pragma unroll
            for (int ks = 0; ks < 2; ++ks)
                ap[0][ks] = ld8(&Pbuf[wave][(0 * 16 + ln) * 72 +
                                            ks * 32 + quad * 8]);
            asm volatile("s_waitcnt lgkmcnt(0)" ::: "memory");
            __builtin_amdgcn_sched_barrier(0);
#pragma unroll
            for (int ks = 0; ks < 2; ++ks)
                ap[1][ks] = ld8(&Pbuf[wave][(1 * 16 + ln) * 72 +
                                            ks * 32 + quad * 8]);

            __builtin_amdgcn_s_setprio(1);            // T5 around PV
#pragma unroll
            for (int n = 0; n < 4; ++n) {
                int row = n * 16 + ln;
#pragma unroll
                for (int ks = 0; ks < 2; ++ks) {
                    short8 bv = ld8(&Vc[row * 64 +
                                        (((ks * 4 + quad) ^ (row & 7)) << 3)]);
#pragma unroll
                    for (int rt = 0; rt < 2; ++rt)
                        o[rt][n] = mfma16(ap[rt][ks], bv, o[rt][n]);
                }
            }
            __builtin_amdgcn_s_setprio(0);
        }

        __syncthreads();
        cur ^= 1;
    }

    int bb = bh / H_, h = bh - bb * H_;
#pragma unroll
    for (int rt = 0; rt < 2; ++rt)
#pragma unroll
        for (int r2 = 0; r2 < 4; ++r2) {
            float l = l_run[rt][r2];
            l += __shfl_xor(l, 1);
            l += __shfl_xor(l, 2);
            l += __shfl_xor(l, 4);
            l += __shfl_xor(l, 8);
            float inv = 1.f / l;
            int row = qrow0 + rt * 16 + quad * 4 + r2;
#pragma unroll
            for (int n = 0; n < 4; ++n) {
                int col = h * 64 + n * 16 + ln;
                attnbf[((size_t)bb * S_ + row) * D_ + col] =
                    __float2bfloat16(o[rt][n][r2] * inv);
            }
        }
}

// ---------------- out projection: BM=128 x BN=64, 36KB LDS, 4 blocks/CU ----
__global__ __launch_bounds__(256, 4)
void gemm_out(const __hip_bfloat16* __restrict__ A,
              const __hip_bfloat16* __restrict__ Bt,
              const float* __restrict__ bias,
              float* __restrict__ Cout) {
    __shared__ __align__(16) char smem[36864];   // 3 x (As 8K + Bs 4K)

    int tid = threadIdx.x, wave = tid >> 6, lane = tid & 63;
    int ln = lane & 15, quad = lane >> 4;
    int lin = blockIdx.y * 12 + blockIdx.x;      // 0..767
    int work = (lin & 7) * 96 + (lin >> 3);
    int mbb = work / 12, nbb = work % 12;
    int mb = mbb * 128, nb = nbb * 64;
    int wm = (wave >> 1) * 64, wn = (wave & 1) * 32;   // wave tile 64x32

    f32x4 acc[4][2];
#pragma unroll
    for (int i = 0; i < 4; ++i)
#pragma unroll
        for (int j = 0; j < 2; ++j) acc[i][j] = (f32x4){0.f, 0.f, 0.f, 0.f};

    auto stage = [&](int k, int bufoff) {        // 3 async16 per thread
        __hip_bfloat16* Asb = (__hip_bfloat16*)(smem + bufoff);
        __hip_bfloat16* Bsb = Asb + 128 * 32;
#pragma unroll
        for (int it = 0; it < 2; ++it) {         // A: 128 rows
            int c = it * 256 + tid;
            int row = c >> 2, cc = c & 3;
            int csw = cc ^ ((row >> 1) & 3);
            async16(A + (size_t)(mb + row) * D_ + k + csw * 8,
                    Asb + it * 2048 + wave * 512);
        }
        {                                        // B: 64 rows
            int c = tid;
            int row = c >> 2, cc = c & 3;
            int csw = cc ^ ((row >> 1) & 3);
            async16(Bt + (size_t)(nb + row) * D_ + k + csw * 8,
                    Bsb + wave * 512);
        }
    };

    auto compute = [&](int bufoff) {
        __hip_bfloat16* As = (__hip_bfloat16*)(smem + bufoff);
        __hip_bfloat16* Bs = As + 128 * 32;
        short8 a[4], b[2];
#pragma unroll
        for (int i = 0; i < 4; ++i) {
            int row = wm + i * 16 + ln;
            a[i] = ld8(As + row * 32 + ((quad ^ ((row >> 1) & 3)) << 3));
        }
#pragma unroll
        for (int j = 0; j < 2; ++j) {
            int row = wn + j * 16 + ln;
            b[j] = ld8(Bs + row * 32 + ((quad ^ ((row >> 1) & 3)) << 3));
        }
#pragma unroll
        for (int i = 0; i < 4; ++i)
#pragma unroll
            for (int j = 0; j < 2; ++j)
                acc[i][j] = mfma16(a[i], b[j], acc[i][j]);
    };

    stage(0, 0);
    stage(32, 12288);
    int cb = 0;
    for (int k = 0; k < D_ - 32; k += 32) {
        asm volatile("s_waitcnt vmcnt(3)" ::: "memory");
        asm volatile("s_barrier" ::: "memory");
        if (k + 64 < D_) {
            int sb = cb + 24576; if (sb >= 36864) sb -= 36864;
            stage(k + 64, sb);
        }
        compute(cb);
        cb += 12288; if (cb >= 36864) cb = 0;
    }
    asm volatile("s_waitcnt vmcnt(0)" ::: "memory");
    asm volatile("s_barrier" ::: "memory");
    compute(cb);

#pragma unroll
    for (int j = 0; j < 2; ++j) {
        int col = nb + wn + j * 16 + ln;
        float bv = bias[col];
#pragma unroll
        for (int i = 0; i < 4; ++i)
#pragma unroll
            for (int r = 0; r < 4; ++r) {
                int row = mb + wm + i * 16 + quad * 4 + r;
                Cout[(size_t)row * D_ + col] = acc[i][j][r] + bv;
            }
    }
}

// ---------------- launch ----------------
extern "C" void kernel_launch(void* const* d_in, const int* in_sizes, int n_in,
                              void* d_out, int out_size, void* d_ws, size_t ws_size,
                              hipStream_t stream) {
    const float* X    = (const float*)d_in[0];
    const float* Wqkv = (const float*)d_in[1];
    const float* bqkv = (const float*)d_in[2];
    const float* Wout = (const float*)d_in[3];
    const float* bout = (const float*)d_in[4];
    float* out = (float*)d_out;

    constexpr size_t SZ_XBF   = (size_t)BS_ * D_ * 2;
    constexpr size_t SZ_WQKVT = (size_t)N3_ * D_ * 2;
    constexpr size_t SZ_WOUTT = (size_t)D_ * D_ * 2;
    constexpr size_t SZ_QKV   = (size_t)B_ * H_ * S_ * HD_ * 2;

    char* w = (char*)d_ws;
    __hip_bfloat16* Xbf    = (__hip_bfloat16*)(w);
    __hip_bfloat16* WqkvT  = (__hip_bfloat16*)(w + SZ_XBF);
    __hip_bfloat16* WoutT  = (__hip_bfloat16*)(w + SZ_XBF + SZ_WQKVT);
    __hip_bfloat16* Qb     = (__hip_bfloat16*)(w + SZ_XBF + SZ_WQKVT + SZ_WOUTT);
    __hip_bfloat16* Kb     = (__hip_bfloat16*)(w + SZ_XBF + SZ_WQKVT + SZ_WOUTT + SZ_QKV);
    __hip_bfloat16* Vtb    = (__hip_bfloat16*)(w + SZ_XBF + SZ_WQKVT + SZ_WOUTT + 2*SZ_QKV);
    __hip_bfloat16* attnbf = (__hip_bfloat16*)(w + SZ_XBF + SZ_WQKVT + SZ_WOUTT + 3*SZ_QKV);
    (void)ws_size; (void)in_sizes; (void)n_in; (void)out_size;

    prep<<<PREP_CAST_BLK + PREP_WQKV_BLK + PREP_WOUT_BLK, 256, 0, stream>>>(
        X, Xbf, Wqkv, WqkvT, Wout, WoutT);

    gemm_qkv<<<dim3(N3_ / 128, BS_ / 128), 256, 0, stream>>>(Xbf, WqkvT, bqkv, Qb, Kb, Vtb);

    attn_flash3<<<dim3(8, B_ * H_), 256, 0, stream>>>(Qb, Kb, Vtb, attnbf);

    gemm_out<<<dim3(D_ / 64, BS_ / 128), 256, 0, stream>>>(attnbf, WoutT, bout, out);
}

// Round 15
// 176.425 us; speedup vs baseline: 1.0188x; 1.0188x over previous
//
#include <hip/hip_runtime.h>
#include <hip/hip_bf16.h>

// Problem constants
#define B_   8
#define S_   1024
#define D_   768
#define H_   12
#define HD_  64
#define BS_  (B_*S_)     // 8192 rows
#define N3_  (3*D_)      // 2304

typedef __attribute__((ext_vector_type(8))) short short8;   // 8 x bf16 (4 VGPRs)
typedef __attribute__((ext_vector_type(4))) float f32x4;

__device__ __forceinline__ short8 ld8(const __hip_bfloat16* p) {
    return *reinterpret_cast<const short8*>(p);
}
__device__ __forceinline__ void st8(__hip_bfloat16* p, short8 v) {
    *reinterpret_cast<short8*>(p) = v;
}
__device__ __forceinline__ f32x4 mfma16(short8 a, short8 b, f32x4 c) {
    return __builtin_amdgcn_mfma_f32_16x16x32_bf16(a, b, c, 0, 0, 0);
}
// async global->LDS, 16B/lane; LDS dest = wave-uniform base + lane*16 (HW adds)
__device__ __forceinline__ void async16(const __hip_bfloat16* g, __hip_bfloat16* l) {
    __builtin_amdgcn_global_load_lds((const __attribute__((address_space(1))) void*)g,
                                     (__attribute__((address_space(3))) void*)l,
                                     16, 0, 0);
}
__device__ __forceinline__ float fast_exp2(float x) {
#if __has_builtin(__builtin_amdgcn_exp2f)
    return __builtin_amdgcn_exp2f(x);
#else
    return __expf(x * 0.69314718056f);
#endif
}

// ---------------- fused prep: cast X + transpose both weights --------------
// R15: cast region deepened 4x (16 floats/thread via 4 coalesced strided
// float4->ushort4 pairs) -> cast grid 6144->1536, prep total 8448->3840
// blocks (33->15 CU-rounds). Prep was round-count-bound (~15-20us for 31MB
// of traffic whose BW floor is ~6us); same traffic, fewer latency epochs.
#define PREP_CAST_BLK 1536          // BS_*D_ / (256*16)
#define PREP_WQKV_BLK 1728          // (N3_/32)*(D_/32)
#define PREP_WOUT_BLK 576           // (D_/32)*(D_/32)
__global__ __launch_bounds__(256)
void prep(const float* __restrict__ X, __hip_bfloat16* __restrict__ Xbf,
          const float* __restrict__ Wqkv, __hip_bfloat16* __restrict__ WqkvT,
          const float* __restrict__ Wout, __hip_bfloat16* __restrict__ WoutT) {
    __shared__ float tile[32][33];
    int b = blockIdx.x, tid = threadIdx.x;
    if (b < PREP_CAST_BLK) {
        int base = b * 4096;                       // 256 threads x 16 floats
#pragma unroll
        for (int rr = 0; rr < 4; ++rr) {
            int i = base + rr * 1024 + tid * 4;    // lane-coalesced float4
            float4 v = *reinterpret_cast<const float4*>(X + i);
            __hip_bfloat16 tmp[4];
            tmp[0] = __float2bfloat16(v.x);
            tmp[1] = __float2bfloat16(v.y);
            tmp[2] = __float2bfloat16(v.z);
            tmp[3] = __float2bfloat16(v.w);
            *reinterpret_cast<ushort4*>(Xbf + i) =
                *reinterpret_cast<const ushort4*>(tmp);   // one 8B store
        }
        return;
    }
    const float* in; __hip_bfloat16* out; int Rr, Cc, bx, by;
    if (b < PREP_CAST_BLK + PREP_WQKV_BLK) {
        int sub = b - PREP_CAST_BLK;
        bx = sub % (N3_ / 32); by = sub / (N3_ / 32);
        in = Wqkv; out = WqkvT; Rr = D_; Cc = N3_;
    } else {
        int sub = b - PREP_CAST_BLK - PREP_WQKV_BLK;
        bx = sub % (D_ / 32); by = sub / (D_ / 32);
        in = Wout; out = WoutT; Rr = D_; Cc = D_;
    }
    int tx = tid & 31, ty = tid >> 5;
    int c0 = bx * 32, r0 = by * 32;
    for (int i = ty; i < 32; i += 8)
        tile[i][tx] = in[(size_t)(r0 + i) * Cc + c0 + tx];
    __syncthreads();
    for (int i = ty; i < 32; i += 8)
        out[(size_t)(c0 + i) * Rr + r0 + tx] = __float2bfloat16(tile[tx][i]);
}

// ---------------- QKV GEMM: round-3 champion, FROZEN -----------------------
// Ledger closed: traffic (R3 null), occupancy up/down (R5/R1/R2 regress),
// stagger (R10 null), barrier-free 1-wave (R11: 2.3x WORSE -- per-SIMD wave
// parallelism is load-bearing). 48.2us is this tile/shape's structural
// optimum. Grid-quantization fixes (smaller tiles / split-K) analyzed R14:
// all net-negative (step time is sync-dominated). Do not touch.
__global__ __launch_bounds__(256)
void gemm_qkv(const __hip_bfloat16* __restrict__ A,
              const __hip_bfloat16* __restrict__ Bt,
              const float* __restrict__ bqkv,
              __hip_bfloat16* __restrict__ Qb,
              __hip_bfloat16* __restrict__ Kb,
              __hip_bfloat16* __restrict__ Vtb) {
    __shared__ __align__(16) char smem[49152];           // 3 x (As 8K + Bs 8K)
    __hip_bfloat16* Ct = (__hip_bfloat16*)smem;          // [128][132] epilogue

    int tid = threadIdx.x, wave = tid >> 6, lane = tid & 63;
    int ln = lane & 15, quad = lane >> 4;
    int lin = blockIdx.y * 18 + blockIdx.x;              // 0..1151
    int work = (lin & 7) * 144 + (lin >> 3);
    int mbb = work / 18, nbb = work % 18;
    int mb = mbb * 128, nb = nbb * 128;
    int wm = (wave >> 1) * 64, wn = (wave & 1) * 64;

    f32x4 acc[4][4];
#pragma unroll
    for (int i = 0; i < 4; ++i)
#pragma unroll
        for (int j = 0; j < 4; ++j) acc[i][j] = (f32x4){0.f, 0.f, 0.f, 0.f};

    auto stage = [&](int k, int bufoff) {   // 4 async16 per thread
        __hip_bfloat16* Asb = (__hip_bfloat16*)(smem + bufoff);
        __hip_bfloat16* Bsb = Asb + 128 * 32;
#pragma unroll
        for (int it = 0; it < 2; ++it) {
            int c = it * 256 + tid;
            int row = c >> 2, cc = c & 3;
            int csw = cc ^ ((row >> 1) & 3);
            async16(A + (size_t)(mb + row) * D_ + k + csw * 8,
                    Asb + it * 2048 + wave * 512);
            async16(Bt + (size_t)(nb + row) * D_ + k + csw * 8,
                    Bsb + it * 2048 + wave * 512);
        }
    };

    auto compute = [&](int bufoff) {
        __hip_bfloat16* As = (__hip_bfloat16*)(smem + bufoff);
        __hip_bfloat16* Bs = As + 128 * 32;
        short8 a[4], b[4];
#pragma unroll
        for (int i = 0; i < 4; ++i) {
            int row = wm + i * 16 + ln;
            a[i] = ld8(As + row * 32 + ((quad ^ ((row >> 1) & 3)) << 3));
        }
#pragma unroll
        for (int j = 0; j < 4; ++j) {
            int row = wn + j * 16 + ln;
            b[j] = ld8(Bs + row * 32 + ((quad ^ ((row >> 1) & 3)) << 3));
        }
#pragma unroll
        for (int i = 0; i < 4; ++i)
#pragma unroll
            for (int j = 0; j < 4; ++j)
                acc[i][j] = mfma16(a[i], b[j], acc[i][j]);
    };

    stage(0, 0);
    stage(32, 16384);
    int cb = 0;
    for (int k = 0; k < D_ - 32; k += 32) {
        asm volatile("s_waitcnt vmcnt(4)" ::: "memory");  // oldest stage done
        asm volatile("s_barrier" ::: "memory");           // visible to all
        if (k + 64 < D_) {
            int sb = cb + 32768; if (sb >= 49152) sb -= 49152;
            stage(k + 64, sb);                            // distance-2 prefetch
        }
        compute(cb);
        cb += 16384; if (cb >= 49152) cb = 0;
    }
    asm volatile("s_waitcnt vmcnt(0)" ::: "memory");      // peeled last iter
    asm volatile("s_barrier" ::: "memory");
    compute(cb);
    __syncthreads();   // all compute done; LDS reusable for epilogue

    // ---- epilogue: one pass through LDS, coalesced 16B stores ----
    int which = nbb / 6;                // 0=Q, 1=K, 2=V
    int nbr = nb - which * D_;
    float qscale = (which == 0) ? (0.125f * 1.44269504089f) : 1.f;

#pragma unroll
    for (int j = 0; j < 4; ++j) {
        int col = wn + j * 16 + ln;
        float bias = bqkv[nb + col];
#pragma unroll
        for (int i = 0; i < 4; ++i)
#pragma unroll
            for (int r = 0; r < 4; ++r) {
                int row = wm + i * 16 + quad * 4 + r;
                __hip_bfloat16 v = __float2bfloat16((acc[i][j][r] + bias) * qscale);
                if (which != 2) Ct[row * 132 + col] = v;
                else            Ct[col * 132 + row] = v;    // [d][s]
            }
    }
    __syncthreads();

    int bb = mb >> 10, sb = mb & 1023;
    if (which != 2) {
        __hip_bfloat16* dst = (which == 0) ? Qb : Kb;
#pragma unroll
        for (int it = 0; it < 8; ++it) {
            int cc = it * 256 + tid;
            int row = cc >> 4, c8 = cc & 15;
            short8 v = ld8(Ct + row * 132 + c8 * 8);
            int gcol = nbr + c8 * 8;
            int h = gcol >> 6, d = gcol & 63;
            int s = sb + row;
            st8(dst + (((size_t)(bb * H_ + h)) * S_ + s) * HD_ + d, v);
        }
    } else {
#pragma unroll
        for (int it = 0; it < 8; ++it) {
            int cc = it * 256 + tid;
            int drow = cc >> 4, s8 = cc & 15;
            short8 v = ld8(Ct + drow * 132 + s8 * 8);
            int gd = nbr + drow;
            int h = gd >> 6, d = gd & 63;
            st8(Vtb + ((size_t)(bb * H_ + h) * HD_ + d) * S_ + sb + s8 * 8, v);
        }
    }
}

// ---------------- causal flash attention v5 (R9 best-measured) -------------
// Balanced strip pairing (2j,2j+1) + XCD-grouped heads + setprio +
// split-lgkm + single __syncthreads per kt. R13's counted-vmcnt variant was
// neutral-to-negative; remaining cost is the in-iteration serial chain.
__global__ __launch_bounds__(256, 3)
void attn_flash3(const __hip_bfloat16* __restrict__ Q,
                 const __hip_bfloat16* __restrict__ K,
                 const __hip_bfloat16* __restrict__ Vt,
                 __hip_bfloat16* __restrict__ attnbf) {
    __shared__ __hip_bfloat16 Kbuf[2][64 * 64];
    __shared__ __hip_bfloat16 Vbuf[2][64 * 64];
    __shared__ __hip_bfloat16 Pbuf[4][32 * 72];

    int tid = threadIdx.x;
    int wave = tid >> 6, lane = tid & 63;
    int ln = lane & 15, quad = lane >> 4;

    int lin = blockIdx.y * 8 + blockIdx.x;   // 0..767, dispatch order
    int xcd = lin & 7;
    int idx = lin >> 3;                      // 0..95
    int jj  = idx & 7;
    int bh  = (idx >> 3) * 8 + xcd;          // head group pinned to one XCD
    int r   = idx >> 5;                      // CU-round 0..2

    const int TBL1[8] = {4, 5, 6, 7, 0, 1, 2, 3};
    const int TBL2[8] = {6, 4, 2, 0, 7, 5, 3, 1};
    int jp = (r == 0) ? jj : (r == 1) ? TBL1[jj] : TBL2[jj];
    int strip = jp * 2 + (wave >> 1);        // waves 0,1 -> 2j; waves 2,3 -> 2j+1
    int qrow0 = strip * 64 + (wave & 1) * 32;
    int last_kt = jp * 2 + 1;

    const __hip_bfloat16* Qbh = Q + (size_t)bh * S_ * HD_;
    const __hip_bfloat16* Kbh = K + (size_t)bh * S_ * HD_;
    const __hip_bfloat16* Vbh = Vt + (size_t)bh * HD_ * S_;

    short8 aq[2][2];
#pragma unroll
    for (int rt = 0; rt < 2; ++rt)
#pragma unroll
        for (int ks = 0; ks < 2; ++ks)
            aq[rt][ks] = ld8(Qbh + (size_t)(qrow0 + rt * 16 + ln) * HD_ +
                             ks * 32 + quad * 8);

    f32x4 o[2][4];
    float l_run[2][4];
#pragma unroll
    for (int rt = 0; rt < 2; ++rt)
#pragma unroll
        for (int n = 0; n < 4; ++n) {
            o[rt][n] = (f32x4){0.f, 0.f, 0.f, 0.f};
            l_run[rt][n] = 0.f;
        }

    auto stage = [&](int kt, int buf) {
        const __hip_bfloat16* gK = Kbh + (size_t)kt * 64 * HD_;
#pragma unroll
        for (int it = 0; it < 2; ++it) {
            int p = it * 256 + tid;
            int row = p >> 3;
            int csw = (p & 7) ^ (row & 7);
            async16(gK + row * HD_ + csw * 8,
                    &Kbuf[buf][it * 2048 + wave * 512]);
            async16(Vbh + (size_t)row * S_ + kt * 64 + csw * 8,
                    &Vbuf[buf][it * 2048 + wave * 512]);
        }
    };

    stage(0, 0);
    __syncthreads();
    int cur = 0;

    for (int kt = 0; kt <= last_kt; ++kt) {
        int kbase = kt * 64;
        if (kt < last_kt) stage(kt + 1, cur ^ 1);

        if (kbase <= qrow0 + 31) {
            const __hip_bfloat16* Kc = Kbuf[cur];
            const __hip_bfloat16* Vc = Vbuf[cur];

            f32x4 s[2][4];
#pragma unroll
            for (int rt = 0; rt < 2; ++rt)
#pragma unroll
                for (int j = 0; j < 4; ++j) s[rt][j] = (f32x4){0.f, 0.f, 0.f, 0.f};
            __builtin_amdgcn_s_setprio(1);            // T5: favor MFMA wave
#pragma unroll
            for (int j = 0; j < 4; ++j) {
                int row = j * 16 + ln;
#pragma unroll
                for (int ks = 0; ks < 2; ++ks) {
                    short8 bk = ld8(&Kc[row * 64 +
                                        (((ks * 4 + quad) ^ (row & 7)) << 3)]);
#pragma unroll
                    for (int rt = 0; rt < 2; ++rt)
                        s[rt][j] = mfma16(aq[rt][ks], bk, s[rt][j]);
                }
            }
            __builtin_amdgcn_s_setprio(0);

            if (kbase + 63 > qrow0) {
#pragma unroll
                for (int rt = 0; rt < 2; ++rt)
#pragma unroll
                    for (int j = 0; j < 4; ++j) {
                        int key = kbase + j * 16 + ln;
#pragma unroll
                        for (int r2 = 0; r2 < 4; ++r2) {
                            int q = qrow0 + rt * 16 + quad * 4 + r2;
                            if (key > q) s[rt][j][r2] = -INFINITY;
                        }
                    }
            }

#pragma unroll
            for (int rt = 0; rt < 2; ++rt)
#pragma unroll
                for (int j = 0; j < 4; ++j)
#pragma unroll
                    for (int r2 = 0; r2 < 4; ++r2)
                        s[rt][j][r2] = fast_exp2(s[rt][j][r2]);
#pragma unroll
            for (int rt = 0; rt < 2; ++rt)
#pragma unroll
                for (int r2 = 0; r2 < 4; ++r2)
                    l_run[rt][r2] += (s[rt][0][r2] + s[rt][1][r2]) +
                                     (s[rt][2][r2] + s[rt][3][r2]);

            // P write-back: rt=0's 16 stores first, then rt=1's 16 (in-order
            // DS retire => lgkmcnt(15) releases rt=0 rows early).
#pragma unroll
            for (int rt = 0; rt < 2; ++rt)
#pragma unroll
                for (int j = 0; j < 4; ++j)
#pragma unroll
                    for (int r2 = 0; r2 < 4; ++r2)
                        Pbuf[wave][(rt * 16 + quad * 4 + r2) * 72 + j * 16 + ln] =
                            __float2bfloat16(s[rt][j][r2]);

            short8 ap[2][2];
            asm volatile("s_waitcnt lgkmcnt(15)" ::: "memory");
            __builtin_amdgcn_sched_barrier(0);
#pragma unroll
            for (int ks = 0; ks < 2; ++ks)
                ap[0][ks] = ld8(&Pbuf[wave][(0 * 16 + ln) * 72 +
                                            ks * 32 + quad * 8]);
            asm volatile("s_waitcnt lgkmcnt(0)" ::: "memory");
            __builtin_amdgcn_sched_barrier(0);
#pragma unroll
            for (int ks = 0; ks < 2; ++ks)
                ap[1][ks] = ld8(&Pbuf[wave][(1 * 16 + ln) * 72 +
                                            ks * 32 + quad * 8]);

            __builtin_amdgcn_s_setprio(1);            // T5 around PV
#pragma unroll
            for (int n = 0; n < 4; ++n) {
                int row = n * 16 + ln;
#pragma unroll
                for (int ks = 0; ks < 2; ++ks) {
                    short8 bv = ld8(&Vc[row * 64 +
                                        (((ks * 4 + quad) ^ (row & 7)) << 3)]);
#pragma unroll
                    for (int rt = 0; rt < 2; ++rt)
                        o[rt][n] = mfma16(ap[rt][ks], bv, o[rt][n]);
                }
            }
            __builtin_amdgcn_s_setprio(0);
        }

        __syncthreads();
        cur ^= 1;
    }

    int bb = bh / H_, h = bh - bb * H_;
#pragma unroll
    for (int rt = 0; rt < 2; ++rt)
#pragma unroll
        for (int r2 = 0; r2 < 4; ++r2) {
            float l = l_run[rt][r2];
            l += __shfl_xor(l, 1);
            l += __shfl_xor(l, 2);
            l += __shfl_xor(l, 4);
            l += __shfl_xor(l, 8);
            float inv = 1.f / l;
            int row = qrow0 + rt * 16 + quad * 4 + r2;
#pragma unroll
            for (int n = 0; n < 4; ++n) {
                int col = h * 64 + n * 16 + ln;
                attnbf[((size_t)bb * S_ + row) * D_ + col] =
                    __float2bfloat16(o[rt][n][r2] * inv);
            }
        }
}

// ---------------- out projection: BM=128 x BN=64, 36KB LDS, 4 blocks/CU ----
__global__ __launch_bounds__(256, 4)
void gemm_out(const __hip_bfloat16* __restrict__ A,
              const __hip_bfloat16* __restrict__ Bt,
              const float* __restrict__ bias,
              float* __restrict__ Cout) {
    __shared__ __align__(16) char smem[36864];   // 3 x (As 8K + Bs 4K)

    int tid = threadIdx.x, wave = tid >> 6, lane = tid & 63;
    int ln = lane & 15, quad = lane >> 4;
    int lin = blockIdx.y * 12 + blockIdx.x;      // 0..767
    int work = (lin & 7) * 96 + (lin >> 3);
    int mbb = work / 12, nbb = work % 12;
    int mb = mbb * 128, nb = nbb * 64;
    int wm = (wave >> 1) * 64, wn = (wave & 1) * 32;   // wave tile 64x32

    f32x4 acc[4][2];
#pragma unroll
    for (int i = 0; i < 4; ++i)
#pragma unroll
        for (int j = 0; j < 2; ++j) acc[i][j] = (f32x4){0.f, 0.f, 0.f, 0.f};

    auto stage = [&](int k, int bufoff) {        // 3 async16 per thread
        __hip_bfloat16* Asb = (__hip_bfloat16*)(smem + bufoff);
        __hip_bfloat16* Bsb = Asb + 128 * 32;
#pragma unroll
        for (int it = 0; it < 2; ++it) {         // A: 128 rows
            int c = it * 256 + tid;
            int row = c >> 2, cc = c & 3;
            int csw = cc ^ ((row >> 1) & 3);
            async16(A + (size_t)(mb + row) * D_ + k + csw * 8,
                    Asb + it * 2048 + wave * 512);
        }
        {                                        // B: 64 rows
            int c = tid;
            int row = c >> 2, cc = c & 3;
            int csw = cc ^ ((row >> 1) & 3);
            async16(Bt + (size_t)(nb + row) * D_ + k + csw * 8,
                    Bsb + wave * 512);
        }
    };

    auto compute = [&](int bufoff) {
        __hip_bfloat16* As = (__hip_bfloat16*)(smem + bufoff);
        __hip_bfloat16* Bs = As + 128 * 32;
        short8 a[4], b[2];
#pragma unroll
        for (int i = 0; i < 4; ++i) {
            int row = wm + i * 16 + ln;
            a[i] = ld8(As + row * 32 + ((quad ^ ((row >> 1) & 3)) << 3));
        }
#pragma unroll
        for (int j = 0; j < 2; ++j) {
            int row = wn + j * 16 + ln;
            b[j] = ld8(Bs + row * 32 + ((quad ^ ((row >> 1) & 3)) << 3));
        }
#pragma unroll
        for (int i = 0; i < 4; ++i)
#pragma unroll
            for (int j = 0; j < 2; ++j)
                acc[i][j] = mfma16(a[i], b[j], acc[i][j]);
    };

    stage(0, 0);
    stage(32, 12288);
    int cb = 0;
    for (int k = 0; k < D_ - 32; k += 32) {
        asm volatile("s_waitcnt vmcnt(3)" ::: "memory");
        asm volatile("s_barrier" ::: "memory");
        if (k + 64 < D_) {
            int sb = cb + 24576; if (sb >= 36864) sb -= 36864;
            stage(k + 64, sb);
        }
        compute(cb);
        cb += 12288; if (cb >= 36864) cb = 0;
    }
    asm volatile("s_waitcnt vmcnt(0)" ::: "memory");
    asm volatile("s_barrier" ::: "memory");
    compute(cb);

#pragma unroll
    for (int j = 0; j < 2; ++j) {
        int col = nb + wn + j * 16 + ln;
        float bv = bias[col];
#pragma unroll
        for (int i = 0; i < 4; ++i)
#pragma unroll
            for (int r = 0; r < 4; ++r) {
                int row = mb + wm + i * 16 + quad * 4 + r;
                Cout[(size_t)row * D_ + col] = acc[i][j][r] + bv;
            }
    }
}

// ---------------- launch ----------------
extern "C" void kernel_launch(void* const* d_in, const int* in_sizes, int n_in,
                              void* d_out, int out_size, void* d_ws, size_t ws_size,
                              hipStream_t stream) {
    const float* X    = (const float*)d_in[0];
    const float* Wqkv = (const float*)d_in[1];
    const float* bqkv = (const float*)d_in[2];
    const float* Wout = (const float*)d_in[3];
    const float* bout = (const float*)d_in[4];
    float* out = (float*)d_out;

    constexpr size_t SZ_XBF   = (size_t)BS_ * D_ * 2;
    constexpr size_t SZ_WQKVT = (size_t)N3_ * D_ * 2;
    constexpr size_t SZ_WOUTT = (size_t)D_ * D_ * 2;
    constexpr size_t SZ_QKV   = (size_t)B_ * H_ * S_ * HD_ * 2;

    char* w = (char*)d_ws;
    __hip_bfloat16* Xbf    = (__hip_bfloat16*)(w);
    __hip_bfloat16* WqkvT  = (__hip_bfloat16*)(w + SZ_XBF);
    __hip_bfloat16* WoutT  = (__hip_bfloat16*)(w + SZ_XBF + SZ_WQKVT);
    __hip_bfloat16* Qb     = (__hip_bfloat16*)(w + SZ_XBF + SZ_WQKVT + SZ_WOUTT);
    __hip_bfloat16* Kb     = (__hip_bfloat16*)(w + SZ_XBF + SZ_WQKVT + SZ_WOUTT + SZ_QKV);
    __hip_bfloat16* Vtb    = (__hip_bfloat16*)(w + SZ_XBF + SZ_WQKVT + SZ_WOUTT + 2*SZ_QKV);
    __hip_bfloat16* attnbf = (__hip_bfloat16*)(w + SZ_XBF + SZ_WQKVT + SZ_WOUTT + 3*SZ_QKV);
    (void)ws_size; (void)in_sizes; (void)n_in; (void)out_size;

    prep<<<PREP_CAST_BLK + PREP_WQKV_BLK + PREP_WOUT_BLK, 256, 0, stream>>>(
        X, Xbf, Wqkv, WqkvT, Wout, WoutT);

    gemm_qkv<<<dim3(N3_ / 128, BS_ / 128), 256, 0, stream>>>(Xbf, WqkvT, bqkv, Qb, Kb, Vtb);

    attn_flash3<<<dim3(8, B_ * H_), 256, 0, stream>>>(Qb, Kb, Vtb, attnbf);

    gemm_out<<<dim3(D_ / 64, BS_ / 128), 256, 0, stream>>>(attnbf, WoutT, bout, out);
}